// Round 4
// baseline (501.442 us; speedup 1.0000x reference)
//
#include <hip/hip_runtime.h>

typedef _Float16 f16;
typedef f16 f16x2 __attribute__((ext_vector_type(2)));
typedef f16 f16x8 __attribute__((ext_vector_type(8)));
typedef float f32x4 __attribute__((ext_vector_type(4)));
typedef float f32x16 __attribute__((ext_vector_type(16)));
typedef unsigned int uint;

#define NCH 16
#define NB 32
#define NH 256
#define NW 256
#define HW 65536
#define CHW 1048576

// ws layout: f16 A-fragments, then f32 bias fragments
#define WF1 0            // [kt4][mt4][lane64][j8] = 8192 f16
#define WF2 8192         // [kt8][mt4][lane64][j8] = 16384
#define WF3 24576        // [kt8][mt4][lane64][j8] = 16384
#define WF4 40960        // [kt8][lane64][j8]      = 4096 (rows 16-31 zero)
#define NF16 45056
#define BIASF32 22528    // float index: [layer3][mt4][hi2][r16] = 384 f32

__global__ void prep_k(const float* __restrict__ w1, const float* __restrict__ w2,
                       const float* __restrict__ w3, const float* __restrict__ w4,
                       const float* __restrict__ b1, const float* __restrict__ b2,
                       const float* __restrict__ b3, float* __restrict__ wsf) {
  f16* wf = (f16*)wsf;
  int id = blockIdx.x * 256 + threadIdx.x;
  if (id < 8192) {
    int j = id & 7, l = (id >> 3) & 63, mt = (id >> 9) & 3, kt = id >> 11;
    int o = mt * 32 + (l & 31), c = kt * 16 + (l >> 5) * 8 + j;
    wf[WF1 + id] = (f16)w1[o * 64 + c];
  } else if (id < 24576) {
    int t = id - 8192;
    int j = t & 7, l = (t >> 3) & 63, mt = (t >> 9) & 3, kt = t >> 11;
    int o = mt * 32 + (l & 31), c = kt * 16 + (l >> 5) * 8 + j;
    wf[WF2 + t] = (f16)w2[o * 128 + c];
  } else if (id < 40960) {
    int t = id - 24576;
    int j = t & 7, l = (t >> 3) & 63, mt = (t >> 9) & 3, kt = t >> 11;
    int o = mt * 32 + (l & 31), c = kt * 16 + (l >> 5) * 8 + j;
    wf[WF3 + t] = (f16)w3[o * 128 + c];
  } else if (id < 45056) {
    int t = id - 40960;
    int j = t & 7, l = (t >> 3) & 63, kt = t >> 9;
    int m = l & 31, hh = l >> 5;
    int c = kt * 16 + hh * 8 + j;
    wf[WF4 + t] = (m < 16) ? (f16)w4[m * 128 + c] : (f16)0.f;
  } else if (id < 45440) {
    int t = id - 45056;
    int r = t & 15, hh = (t >> 4) & 1, mt = (t >> 5) & 3, ly = t >> 7;
    const float* bb = (ly == 0) ? b1 : (ly == 1) ? b2 : b3;
    wsf[BIASF32 + t] = bb[mt * 32 + (r & 3) + 8 * (r >> 2) + 4 * hh];
  }
}

__device__ __forceinline__ void pl32swap(uint& a, uint& b) {
  asm volatile("v_permlane32_swap_b32 %0, %1" : "+v"(a), "+v"(b));
}

__device__ __forceinline__ f16x8 mk8(uint a, uint b, uint c, uint d) {
  union { uint u[4]; f16x8 v; } z;
  z.u[0] = a; z.u[1] = b; z.u[2] = c; z.u[3] = d;
  return z.v;
}

// Batched A-fragment load: issue all NF global loads up-front (one vmcnt batch)
template <int NF>
__device__ __forceinline__ void load_frags(const f16* __restrict__ base, int lane,
                                           f16x8* __restrict__ A) {
  const f16x8* p = (const f16x8*)base + lane;
#pragma unroll
  for (int i = 0; i < NF; ++i) A[i] = p[i * 64];
}

// MFMA compute for one 128-out layer, A already in registers
template <int NKT>
__device__ __forceinline__ void gemm_compute(const f16x8* __restrict__ A,
                                             const float* __restrict__ bfrag,
                                             int lane, int hi,
                                             const f16x8 B[NKT], f32x16 acc[4]) {
#pragma unroll
  for (int mt = 0; mt < 4; ++mt) {
    const f32x4* bp = (const f32x4*)(bfrag + (mt * 2 + hi) * 16);
#pragma unroll
    for (int q = 0; q < 4; ++q) {
      f32x4 bv = bp[q];
#pragma unroll
      for (int e = 0; e < 4; ++e) acc[mt][q * 4 + e] = bv[e];
    }
  }
#pragma unroll
  for (int kt = 0; kt < NKT; ++kt) {
#pragma unroll
    for (int mt = 0; mt < 4; ++mt) {
      acc[mt] = __builtin_amdgcn_mfma_f32_32x32x16_f16(A[kt * 4 + mt], B[kt], acc[mt], 0, 0, 0);
    }
  }
}

// lrelu (f32) -> f16 pack -> permlane re-distribution into next layer's B-frags
__device__ __forceinline__ void epilogue_swap(const f32x16 acc[4], f16x8 Bn[8]) {
  uint w[32];
#pragma unroll
  for (int mt = 0; mt < 4; ++mt) {
#pragma unroll
    for (int i = 0; i < 8; ++i) {
      float v0 = acc[mt][2 * i], v1 = acc[mt][2 * i + 1];
      v0 = fmaxf(v0, 0.01f * v0);
      v1 = fmaxf(v1, 0.01f * v1);
      f16x2 t; t[0] = (f16)v0; t[1] = (f16)v1;
      w[mt * 8 + i] = __builtin_bit_cast(uint, t);
    }
  }
#pragma unroll
  for (int kt = 0; kt < 8; ++kt) {
    int mt = kt >> 1, sub = kt & 1;
    int W = mt * 8 + sub * 4;
    uint a0 = w[W], a1 = w[W + 1], a2 = w[W + 2], a3 = w[W + 3];
    pl32swap(a0, a2);
    pl32swap(a1, a3);
    Bn[kt] = mk8(a0, a1, a2, a3);
  }
}

__global__ __launch_bounds__(256, 2)
void nca_mlp_k(const float* __restrict__ x, const float* __restrict__ wsf,
               const float* __restrict__ mask, float* __restrict__ xn) {
  __shared__ float xt[NCH][6][34];  // 13056 B
  const int tid = threadIdx.x;
  const int lane = tid & 63;
  const int wv = tid >> 6;
  const int px = lane & 31;
  const int hi = lane >> 5;
  const int c0 = blockIdx.x * 32;
  const int r0 = blockIdx.y * 4;
  const int b = blockIdx.z;

  const f16* wf = (const f16*)wsf;
  const float* biasf = wsf + BIASF32;

  // ---- prefetch L1 A-frags (latency hidden under staging + perception) ----
  f16x8 A1[16];
  load_frags<16>(wf + WF1, lane, A1);

  // ---- stage x tile (zero-padded) ----
  {
    const float* xb = x + (size_t)b * CHW;
    for (int i = tid; i < NCH * 6 * 34; i += 256) {
      int seg = i / 34;
      int cc = i - seg * 34;
      int ch = seg & 15, rr = seg >> 4;
      int gr = r0 - 1 + rr, gc = c0 - 1 + cc;
      float v = 0.f;
      if ((unsigned)gr < NH && (unsigned)gc < NW) v = xb[(ch << 16) + (gr << 8) + gc];
      xt[ch][rr][cc] = v;
    }
  }
  __syncthreads();

  // ---- perception: emit y directly as L1 B-fragments ----
  f16x8 B1[4];
  {
    uint yw[16];
#pragma unroll
    for (int kt = 0; kt < 4; ++kt) {
#pragma unroll
      for (int cp = 0; cp < 2; ++cp) {
        int c = kt * 4 + hi * 2 + cp;
        float v00 = xt[c][wv + 0][px + 0], v01 = xt[c][wv + 0][px + 1], v02 = xt[c][wv + 0][px + 2];
        float v10 = xt[c][wv + 1][px + 0], v11 = xt[c][wv + 1][px + 1], v12 = xt[c][wv + 1][px + 2];
        float v20 = xt[c][wv + 2][px + 0], v21 = xt[c][wv + 2][px + 1], v22 = xt[c][wv + 2][px + 2];
        float rs0 = v00 + v01 + v02, rs1 = v10 + v11 + v12, rs2 = v20 + v21 + v22;
        float fid = v11;
        float fsx = (v02 - v00) + (v22 - v20) + 2.f * (v12 - v10);
        float fsy = (rs2 - rs0) + (v21 - v01);
        float flap = (rs0 + rs1 + rs2) - 9.f * v11;
        f16x2 t0; t0[0] = (f16)fid; t0[1] = (f16)fsx;
        f16x2 t1; t1[0] = (f16)fsy; t1[1] = (f16)flap;
        yw[kt * 4 + cp * 2 + 0] = __builtin_bit_cast(uint, t0);
        yw[kt * 4 + cp * 2 + 1] = __builtin_bit_cast(uint, t1);
      }
    }
#pragma unroll
    for (int kt = 0; kt < 4; ++kt)
      B1[kt] = mk8(yw[kt * 4], yw[kt * 4 + 1], yw[kt * 4 + 2], yw[kt * 4 + 3]);
  }

  f32x16 acc[4];
  f16x8 B2[8], B3[8], B4[8];

  // L1
  gemm_compute<4>(A1, biasf, lane, hi, B1, acc);
  // issue L2 A-loads, then epilogue VALU overlaps their latency
  f16x8 A2[32];
  load_frags<32>(wf + WF2, lane, A2);
  epilogue_swap(acc, B2);

  // L2
  gemm_compute<8>(A2, biasf + 128, lane, hi, B2, acc);
  f16x8 A3[32];
  load_frags<32>(wf + WF3, lane, A3);
  epilogue_swap(acc, B3);

  // L3
  gemm_compute<8>(A3, biasf + 256, lane, hi, B3, acc);
  f16x8 A4[8];
  load_frags<8>(wf + WF4, lane, A4);
  epilogue_swap(acc, B4);

  // ---- layer 4: dy (16 out, M padded to 32) ----
  f32x16 a4;
#pragma unroll
  for (int r = 0; r < 16; ++r) a4[r] = 0.f;
#pragma unroll
  for (int kt = 0; kt < 8; ++kt)
    a4 = __builtin_amdgcn_mfma_f32_32x32x16_f16(A4[kt], B4[kt], a4, 0, 0, 0);

  // ---- update: x_new = x + dy * mask ----
  {
    const int row = r0 + wv, col = c0 + px;
    const float mv = mask[(size_t)b * HW + (row << 8) + col];
    float* xo = xn + (size_t)b * CHW + (row << 8) + col;
#pragma unroll
    for (int r = 0; r < 8; ++r) {
      int ch = (r & 3) + 8 * (r >> 2) + 4 * hi;
      float xv = xt[ch][wv + 1][px + 1];
      xo[(size_t)ch << 16] = xv + a4[r] * mv;
    }
  }
}

// alive factor: row-block with LDS horizontal-max sharing; zero dead pixels
__global__ void alive_scale_k(const float* __restrict__ x, float* __restrict__ xn) {
  __shared__ float pm[4][258];
  const int col = threadIdx.x;
  const int row = blockIdx.x;
  const int b = blockIdx.y;
  const float NEG = -3.0e38f;
  float v0 = NEG, v1 = NEG, v2 = NEG, v3 = NEG;
  const size_t base0 = (size_t)b * CHW + ((size_t)row << 8) + col;
#pragma unroll
  for (int dr = -1; dr <= 1; ++dr) {
    int rr = row + dr;
    if ((unsigned)rr < NH) {
      long o = (long)base0 + dr * NW;
      v0 = fmaxf(v0, x[o]);
      v1 = fmaxf(v1, x[o + HW]);
      v2 = fmaxf(v2, xn[o]);
      v3 = fmaxf(v3, xn[o + HW]);
    }
  }
  pm[0][col + 1] = v0;
  pm[1][col + 1] = v1;
  pm[2][col + 1] = v2;
  pm[3][col + 1] = v3;
  if (col == 0) {
#pragma unroll
    for (int f = 0; f < 4; ++f) { pm[f][0] = NEG; pm[f][257] = NEG; }
  }
  __syncthreads();
  float p0 = fmaxf(fmaxf(pm[0][col], pm[0][col + 1]), pm[0][col + 2]);
  float p1 = fmaxf(fmaxf(pm[1][col], pm[1][col + 1]), pm[1][col + 2]);
  float p2 = fmaxf(fmaxf(pm[2][col], pm[2][col + 1]), pm[2][col + 2]);
  float p3 = fmaxf(fmaxf(pm[3][col], pm[3][col + 1]), pm[3][col + 2]);
  bool alive = ((fabsf(p0) + fabsf(p1)) > 0.01f) && ((fabsf(p2) + fabsf(p3)) > 0.01f);
  if (!alive) {
#pragma unroll
    for (int ch = 0; ch < NCH; ++ch) xn[base0 + ((size_t)ch << 16)] = 0.f;
  }
}

extern "C" void kernel_launch(void* const* d_in, const int* in_sizes, int n_in,
                              void* d_out, int out_size, void* d_ws, size_t ws_size,
                              hipStream_t stream) {
  const float* x    = (const float*)d_in[0];
  const float* w1   = (const float*)d_in[1];
  const float* b1   = (const float*)d_in[2];
  const float* w2   = (const float*)d_in[3];
  const float* b2   = (const float*)d_in[4];
  const float* w3   = (const float*)d_in[5];
  const float* b3   = (const float*)d_in[6];
  const float* w4   = (const float*)d_in[7];
  const float* mask = (const float*)d_in[8];

  float* wsf = (float*)d_ws;
  float* xn = (float*)d_out;

  prep_k<<<178, 256, 0, stream>>>(w1, w2, w3, w4, b1, b2, b3, wsf);
  nca_mlp_k<<<dim3(NW / 32, NH / 4, NB), 256, 0, stream>>>(x, wsf, mask, xn);
  alive_scale_k<<<dim3(NH, NB), 256, 0, stream>>>(x, xn);
}

// Round 5
// 343.212 us; speedup vs baseline: 1.4610x; 1.4610x over previous
//
#include <hip/hip_runtime.h>

typedef _Float16 f16;
typedef f16 f16x2 __attribute__((ext_vector_type(2)));
typedef f16 f16x8 __attribute__((ext_vector_type(8)));
typedef float f32x4 __attribute__((ext_vector_type(4)));
typedef float f32x16 __attribute__((ext_vector_type(16)));
typedef unsigned int uint;

#define NCH 16
#define NB 32
#define NH 256
#define NW 256
#define HW 65536
#define CHW 1048576

// ws layout: f16 A-fragments, then f32 bias fragments (same image copied to LDS)
#define WF1 0            // [kt4][mt4][lane64][j8] = 8192 f16   (byte 0)
#define WF2 8192         // byte 16384
#define WF3 24576        // byte 49152
#define WF4 40960        // byte 81920
#define BIAS_BYTE 90112  // 384 f32 bias frags at f16-index 45056
#define WS_BYTES 91648   // total weight+bias image
#define LDS_XT_OFF 91648
#define XT_ELEMS (16*18*34)           // 9792
#define LDS_TOTAL (WS_BYTES + XT_ELEMS*4)   // 130816

// xt layout: [rr 18][ch 16][cc 34]
#define XT(c, r, cc) xt[(((r)*16 + (c))*34) + (cc)]

__global__ void prep_k(const float* __restrict__ w1, const float* __restrict__ w2,
                       const float* __restrict__ w3, const float* __restrict__ w4,
                       const float* __restrict__ b1, const float* __restrict__ b2,
                       const float* __restrict__ b3, float* __restrict__ wsf) {
  f16* wf = (f16*)wsf;
  int id = blockIdx.x * 256 + threadIdx.x;
  if (id < 8192) {
    int j = id & 7, l = (id >> 3) & 63, mt = (id >> 9) & 3, kt = id >> 11;
    int o = mt * 32 + (l & 31), c = kt * 16 + (l >> 5) * 8 + j;
    wf[WF1 + id] = (f16)w1[o * 64 + c];
  } else if (id < 24576) {
    int t = id - 8192;
    int j = t & 7, l = (t >> 3) & 63, mt = (t >> 9) & 3, kt = t >> 11;
    int o = mt * 32 + (l & 31), c = kt * 16 + (l >> 5) * 8 + j;
    wf[WF2 + t] = (f16)w2[o * 128 + c];
  } else if (id < 40960) {
    int t = id - 24576;
    int j = t & 7, l = (t >> 3) & 63, mt = (t >> 9) & 3, kt = t >> 11;
    int o = mt * 32 + (l & 31), c = kt * 16 + (l >> 5) * 8 + j;
    wf[WF3 + t] = (f16)w3[o * 128 + c];
  } else if (id < 45056) {
    int t = id - 40960;
    int j = t & 7, l = (t >> 3) & 63, kt = t >> 9;
    int m = l & 31, hh = l >> 5;
    int c = kt * 16 + hh * 8 + j;
    wf[WF4 + t] = (m < 16) ? (f16)w4[m * 128 + c] : (f16)0.f;
  } else if (id < 45440) {
    int t = id - 45056;
    int r = t & 15, hh = (t >> 4) & 1, mt = (t >> 5) & 3, ly = t >> 7;
    const float* bb = (ly == 0) ? b1 : (ly == 1) ? b2 : b3;
    ((float*)(wf + 45056))[t] = bb[mt * 32 + (r & 3) + 8 * (r >> 2) + 4 * hh];
  }
}

__device__ __forceinline__ void pl32swap(uint& a, uint& b) {
  asm volatile("v_permlane32_swap_b32 %0, %1" : "+v"(a), "+v"(b));
}

__device__ __forceinline__ f16x8 mk8(uint a, uint b, uint c, uint d) {
  union { uint u[4]; f16x8 v; } z;
  z.u[0] = a; z.u[1] = b; z.u[2] = c; z.u[3] = d;
  return z.v;
}

// One 128-out layer, A-frags + bias read from LDS
template <int NKT>
__device__ __forceinline__ void gemm_lds(const unsigned char* __restrict__ smem,
                                         int wfByte, int biasFloatOff,
                                         int lane, int hi,
                                         const f16x8* __restrict__ B, f32x16 acc[4]) {
  const float* bf = (const float*)(smem + BIAS_BYTE) + biasFloatOff;
#pragma unroll
  for (int mt = 0; mt < 4; ++mt) {
    const f32x4* bp = (const f32x4*)(bf + (mt * 2 + hi) * 16);
#pragma unroll
    for (int q = 0; q < 4; ++q) {
      f32x4 bv = bp[q];
#pragma unroll
      for (int e = 0; e < 4; ++e) acc[mt][q * 4 + e] = bv[e];
    }
  }
  const f16x8* A = (const f16x8*)(smem + wfByte) + lane;
#pragma unroll
  for (int kt = 0; kt < NKT; ++kt) {
#pragma unroll
    for (int mt = 0; mt < 4; ++mt) {
      acc[mt] = __builtin_amdgcn_mfma_f32_32x32x16_f16(A[(kt * 4 + mt) * 64], B[kt], acc[mt], 0, 0, 0);
    }
  }
}

// lrelu (f32) -> f16 pack -> permlane re-distribution into next layer's B-frags
__device__ __forceinline__ void epilogue_swap(const f32x16 acc[4], f16x8 Bn[8]) {
  uint w[32];
#pragma unroll
  for (int mt = 0; mt < 4; ++mt) {
#pragma unroll
    for (int i = 0; i < 8; ++i) {
      float v0 = acc[mt][2 * i], v1 = acc[mt][2 * i + 1];
      v0 = fmaxf(v0, 0.01f * v0);
      v1 = fmaxf(v1, 0.01f * v1);
      f16x2 t; t[0] = (f16)v0; t[1] = (f16)v1;
      w[mt * 8 + i] = __builtin_bit_cast(uint, t);
    }
  }
#pragma unroll
  for (int kt = 0; kt < 8; ++kt) {
    int mt = kt >> 1, sub = kt & 1;
    int W = mt * 8 + sub * 4;
    uint a0 = w[W], a1 = w[W + 1], a2 = w[W + 2], a3 = w[W + 3];
    pl32swap(a0, a2);
    pl32swap(a1, a3);
    Bn[kt] = mk8(a0, a1, a2, a3);
  }
}

__global__ __launch_bounds__(1024)
void nca_mlp_k(const float* __restrict__ x, const float* __restrict__ wsf,
               const float* __restrict__ mask, float* __restrict__ xn) {
  extern __shared__ unsigned char smem[];
  const int tid = threadIdx.x;
  const int lane = tid & 63;
  const int wv = tid >> 6;      // 0..15 = row within tile
  const int px = lane & 31;
  const int hi = lane >> 5;
  const int c0 = blockIdx.x * 32;
  const int r0 = blockIdx.y * 16;
  const int b = blockIdx.z;

  // ---- stage weights+bias image into LDS (linear 16B copy) ----
  {
    const uint4* src = (const uint4*)wsf;
    uint4* dst = (uint4*)smem;
#pragma unroll
    for (int i = 0; i < 6; ++i) {
      int idx = tid + i * 1024;
      if (idx < WS_BYTES / 16) dst[idx] = src[idx];
    }
  }
  // ---- stage x tile (zero-padded halo) ----
  float* xt = (float*)(smem + LDS_XT_OFF);
  {
    const float* xb = x + (size_t)b * CHW;
    for (int i = tid; i < XT_ELEMS; i += 1024) {
      int seg = i / 34;
      int cc = i - seg * 34;
      int ch = seg & 15, rr = seg >> 4;
      int gr = r0 - 1 + rr, gc = c0 - 1 + cc;
      float v = 0.f;
      if ((unsigned)gr < NH && (unsigned)gc < NW) v = xb[(ch << 16) + (gr << 8) + gc];
      xt[i] = v;
    }
  }
  __syncthreads();

  // ---- perception: emit y directly as L1 B-fragments ----
  f16x8 B1[4];
  {
    uint yw[16];
#pragma unroll
    for (int kt = 0; kt < 4; ++kt) {
#pragma unroll
      for (int cp = 0; cp < 2; ++cp) {
        int c = kt * 4 + hi * 2 + cp;
        float v00 = XT(c, wv + 0, px + 0), v01 = XT(c, wv + 0, px + 1), v02 = XT(c, wv + 0, px + 2);
        float v10 = XT(c, wv + 1, px + 0), v11 = XT(c, wv + 1, px + 1), v12 = XT(c, wv + 1, px + 2);
        float v20 = XT(c, wv + 2, px + 0), v21 = XT(c, wv + 2, px + 1), v22 = XT(c, wv + 2, px + 2);
        float rs0 = v00 + v01 + v02, rs1 = v10 + v11 + v12, rs2 = v20 + v21 + v22;
        float fid = v11;
        float fsx = (v02 - v00) + (v22 - v20) + 2.f * (v12 - v10);
        float fsy = (rs2 - rs0) + (v21 - v01);
        float flap = (rs0 + rs1 + rs2) - 9.f * v11;
        f16x2 t0; t0[0] = (f16)fid; t0[1] = (f16)fsx;
        f16x2 t1; t1[0] = (f16)fsy; t1[1] = (f16)flap;
        yw[kt * 4 + cp * 2 + 0] = __builtin_bit_cast(uint, t0);
        yw[kt * 4 + cp * 2 + 1] = __builtin_bit_cast(uint, t1);
      }
    }
#pragma unroll
    for (int kt = 0; kt < 4; ++kt)
      B1[kt] = mk8(yw[kt * 4], yw[kt * 4 + 1], yw[kt * 4 + 2], yw[kt * 4 + 3]);
  }

  f32x16 acc[4];
  f16x8 B2[8], B3[8], B4[8];

  gemm_lds<4>(smem, WF1 * 2, 0, lane, hi, B1, acc);
  epilogue_swap(acc, B2);
  gemm_lds<8>(smem, WF2 * 2, 128, lane, hi, B2, acc);
  epilogue_swap(acc, B3);
  gemm_lds<8>(smem, WF3 * 2, 256, lane, hi, B3, acc);
  epilogue_swap(acc, B4);

  // ---- layer 4: dy (16 out, M padded to 32), A from LDS ----
  f32x16 a4;
#pragma unroll
  for (int r = 0; r < 16; ++r) a4[r] = 0.f;
  {
    const f16x8* A4 = (const f16x8*)(smem + WF4 * 2) + lane;
#pragma unroll
    for (int kt = 0; kt < 8; ++kt)
      a4 = __builtin_amdgcn_mfma_f32_32x32x16_f16(A4[kt * 64], B4[kt], a4, 0, 0, 0);
  }

  // ---- update: x_new = x + dy * mask ----
  {
    const int row = r0 + wv, col = c0 + px;
    const float mv = mask[(size_t)b * HW + (row << 8) + col];
    float* xo = xn + (size_t)b * CHW + (row << 8) + col;
#pragma unroll
    for (int r = 0; r < 8; ++r) {
      int ch = (r & 3) + 8 * (r >> 2) + 4 * hi;
      float xv = XT(ch, wv + 1, px + 1);
      xo[(size_t)ch << 16] = xv + a4[r] * mv;
    }
  }
}

// alive factor: row-block with LDS horizontal-max sharing; zero dead pixels
__global__ void alive_scale_k(const float* __restrict__ x, float* __restrict__ xn) {
  __shared__ float pm[4][258];
  const int col = threadIdx.x;
  const int row = blockIdx.x;
  const int b = blockIdx.y;
  const float NEG = -3.0e38f;
  float v0 = NEG, v1 = NEG, v2 = NEG, v3 = NEG;
  const size_t base0 = (size_t)b * CHW + ((size_t)row << 8) + col;
#pragma unroll
  for (int dr = -1; dr <= 1; ++dr) {
    int rr = row + dr;
    if ((unsigned)rr < NH) {
      long o = (long)base0 + dr * NW;
      v0 = fmaxf(v0, x[o]);
      v1 = fmaxf(v1, x[o + HW]);
      v2 = fmaxf(v2, xn[o]);
      v3 = fmaxf(v3, xn[o + HW]);
    }
  }
  pm[0][col + 1] = v0;
  pm[1][col + 1] = v1;
  pm[2][col + 1] = v2;
  pm[3][col + 1] = v3;
  if (col == 0) {
#pragma unroll
    for (int f = 0; f < 4; ++f) { pm[f][0] = NEG; pm[f][257] = NEG; }
  }
  __syncthreads();
  float p0 = fmaxf(fmaxf(pm[0][col], pm[0][col + 1]), pm[0][col + 2]);
  float p1 = fmaxf(fmaxf(pm[1][col], pm[1][col + 1]), pm[1][col + 2]);
  float p2 = fmaxf(fmaxf(pm[2][col], pm[2][col + 1]), pm[2][col + 2]);
  float p3 = fmaxf(fmaxf(pm[3][col], pm[3][col + 1]), pm[3][col + 2]);
  bool alive = ((fabsf(p0) + fabsf(p1)) > 0.01f) && ((fabsf(p2) + fabsf(p3)) > 0.01f);
  if (!alive) {
#pragma unroll
    for (int ch = 0; ch < NCH; ++ch) xn[base0 + ((size_t)ch << 16)] = 0.f;
  }
}

extern "C" void kernel_launch(void* const* d_in, const int* in_sizes, int n_in,
                              void* d_out, int out_size, void* d_ws, size_t ws_size,
                              hipStream_t stream) {
  const float* x    = (const float*)d_in[0];
  const float* w1   = (const float*)d_in[1];
  const float* b1   = (const float*)d_in[2];
  const float* w2   = (const float*)d_in[3];
  const float* b2   = (const float*)d_in[4];
  const float* w3   = (const float*)d_in[5];
  const float* b3   = (const float*)d_in[6];
  const float* w4   = (const float*)d_in[7];
  const float* mask = (const float*)d_in[8];

  float* wsf = (float*)d_ws;
  float* xn = (float*)d_out;

  // allow >64KB dynamic LDS (idempotent, host-side, capture-safe)
  hipFuncSetAttribute(reinterpret_cast<const void*>(nca_mlp_k),
                      hipFuncAttributeMaxDynamicSharedMemorySize, LDS_TOTAL);

  prep_k<<<178, 256, 0, stream>>>(w1, w2, w3, w4, b1, b2, b3, wsf);
  nca_mlp_k<<<dim3(NW / 32, NH / 16, NB), 1024, LDS_TOTAL, stream>>>(x, wsf, mask, xn);
  alive_scale_k<<<dim3(NH, NB), 256, 0, stream>>>(x, xn);
}